// Round 4
// baseline (749.536 us; speedup 1.0000x reference)
//
#include <hip/hip_runtime.h>
#include <math.h>
#include <string.h>

#define NXG 512
#define NPTS (NXG * NXG)
#define NB 4
#define NT 256
#define NM 256
#define K 16                // steps per chunk (halo width 2K = 32)
#define NCH (NT / K)        // 16 chunks
#define WROWS 128           // window rows (64 interior + 2*32 halo)
#define WCOLS 128           // window cols
#define NTHR 1024           // 16 row-groups x 64 cols; 8x2 cells per thread
#define NTILES 64           // 8x8 tiles (64x64 interior)
#define LROWS 72            // LDS slots: (16+2 pad) groups x 4 published rows

// DPP wave shifts (lane+-1). Junk lands only at window cols 0,1,126,127 —
// garbage-tolerant by the 32-wide col-halo argument (reach <= col 31 after
// 16 steps). Semantics (verified in passing kernels): dpp_left(v) = left
// neighbor lane's v; dpp_right(v) = right neighbor lane's v.
__device__ __forceinline__ float dpp_left(float v) {
    return __int_as_float(__builtin_amdgcn_mov_dpp(__float_as_int(v),
                                                   0x138, 0xf, 0xf, true));
}
__device__ __forceinline__ float dpp_right(float v) {
    return __int_as_float(__builtin_amdgcn_mov_dpp(__float_as_int(v),
                                                   0x130, 0xf, 0xf, true));
}

// ---------------------------------------------------------------------------
// One row (2 cols): reads cur rows + old dst[r] (previous field), writes the
// new field IN PLACE into dst[r].
// ---------------------------------------------------------------------------
__device__ __forceinline__ void row_calc(
    const float (&cur)[8][2], float (&dst)[8][2],
    const float (&v2R)[8][2], int r,
    const float* __restrict__ xm2, const float* __restrict__ xm1,
    const float* __restrict__ xp1, const float* __restrict__ xp2)
{
    // y = window cols c0-2 .. c0+3 of row r
    float y[6] = {dpp_left(cur[r][0]), dpp_left(cur[r][1]),
                  cur[r][0], cur[r][1],
                  dpp_right(cur[r][0]), dpp_right(cur[r][1])};
#pragma unroll
    for (int c = 0; c < 2; ++c) {
        float cc = cur[r][c];
        float sum1 = (xm1[c] + xp1[c]) + (y[c + 1] + y[c + 3]);
        float sum2 = (xm2[c] + xp2[c]) + (y[c] + y[c + 4]);
        float w = fmaf(-60.0f, cc, fmaf(16.0f, sum1, -sum2));
        dst[r][c] = fmaf(v2R[r][c], w, fmaf(2.0f, cc, -dst[r][c]));
    }
}

// ---------------------------------------------------------------------------
// 8 rows/thread: rows 2-5 are register-only (issued first, overlapping the
// 4 halo ds_reads); rows 0,1,6,7 need halo rows and are published to LDS.
// Halo: above group's rows 6,7 (slots base-2, base-1), below group's rows
// 0,1 (slots base+4, base+5).
// ---------------------------------------------------------------------------
__device__ __forceinline__ void do_step(
    const float* __restrict__ Lc, float* __restrict__ Ln,
    const float (&v2R)[8][2], float (&cur)[8][2], float (&nw)[8][2],
    int base, int c0)
{
    float2 a2 = *(const float2*)&Lc[(base - 2) * WCOLS + c0];  // row r0-2
    float2 b2 = *(const float2*)&Lc[(base - 1) * WCOLS + c0];  // row r0-1
    float2 c2 = *(const float2*)&Lc[(base + 4) * WCOLS + c0];  // row r0+8
    float2 d2 = *(const float2*)&Lc[(base + 5) * WCOLS + c0];  // row r0+9

    // interior rows — no LDS dependency, hide halo-read latency
    row_calc(cur, nw, v2R, 2, cur[0], cur[1], cur[3], cur[4]);
    row_calc(cur, nw, v2R, 3, cur[1], cur[2], cur[4], cur[5]);
    row_calc(cur, nw, v2R, 4, cur[2], cur[3], cur[5], cur[6]);
    row_calc(cur, nw, v2R, 5, cur[3], cur[4], cur[6], cur[7]);

    float ha[2] = {a2.x, a2.y};
    float hb[2] = {b2.x, b2.y};
    row_calc(cur, nw, v2R, 0, ha, hb, cur[1], cur[2]);
    *(float2*)&Ln[(base + 0) * WCOLS + c0] = make_float2(nw[0][0], nw[0][1]);
    row_calc(cur, nw, v2R, 1, hb, cur[0], cur[2], cur[3]);
    *(float2*)&Ln[(base + 1) * WCOLS + c0] = make_float2(nw[1][0], nw[1][1]);

    float hc[2] = {c2.x, c2.y};
    float hd[2] = {d2.x, d2.y};
    row_calc(cur, nw, v2R, 6, cur[4], cur[5], cur[7], hc);
    *(float2*)&Ln[(base + 2) * WCOLS + c0] = make_float2(nw[6][0], nw[6][1]);
    row_calc(cur, nw, v2R, 7, cur[5], cur[6], hc, hd);
    *(float2*)&Ln[(base + 3) * WCOLS + c0] = make_float2(nw[7][0], nw[7][1]);
}

// ---------------------------------------------------------------------------
// Rare post-step patch: injection add (+ LDS boundary refresh for published
// rows 0,1,6,7), then measurement reads of the PATCHED new field.
// cells 0..15 = (row<<1)|col, row 0..7, col 0..1.
// ---------------------------------------------------------------------------
__device__ __forceinline__ void patch_step(
    float (&f)[8][2], float* __restrict__ Ln, float* __restrict__ out,
    int base, int c0, int injCell, float addv,
    int m1Cell, int m1Addr, int m2Cell, int m2Addr, int n)
{
    if (injCell >= 0) {
#pragma unroll
        for (int r = 0; r < 8; ++r)
#pragma unroll
            for (int c = 0; c < 2; ++c)
                if (((r << 1) | c) == injCell) f[r][c] += addv;
        int ir = injCell >> 1;
        if (ir == 0) *(float2*)&Ln[(base + 0) * WCOLS + c0] = make_float2(f[0][0], f[0][1]);
        if (ir == 1) *(float2*)&Ln[(base + 1) * WCOLS + c0] = make_float2(f[1][0], f[1][1]);
        if (ir == 6) *(float2*)&Ln[(base + 2) * WCOLS + c0] = make_float2(f[6][0], f[6][1]);
        if (ir == 7) *(float2*)&Ln[(base + 3) * WCOLS + c0] = make_float2(f[7][0], f[7][1]);
    }
    if (m1Cell >= 0) {
        float v = 0.0f;
#pragma unroll
        for (int r = 0; r < 8; ++r)
#pragma unroll
            for (int c = 0; c < 2; ++c)
                if (((r << 1) | c) == m1Cell) v = f[r][c];
        out[m1Addr | n] = v;
    }
    if (m2Cell >= 0) {
        float v = 0.0f;
#pragma unroll
        for (int r = 0; r < 8; ++r)
#pragma unroll
            for (int c = 0; c < 2; ++c)
                if (((r << 1) | c) == m2Cell) v = f[r][c];
        out[m2Addr | n] = v;
    }
}

// ---------------------------------------------------------------------------
__global__ __launch_bounds__(NTHR, 4) void chunk_kernel(
    const float* __restrict__ x,       // (4,1,256,256) — used by chunk 0 only
    const float* __restrict__ se,      // (64,)
    float* __restrict__ out,           // (4,1,256,256) = [b][m][t]
    const float* __restrict__ gA,      // f_{n0}   (unused when n0==0: zeros)
    const float* __restrict__ gB,      // f_{n0-1} (unused when n0==0)
    float* __restrict__ wA,            // f_{n0+K}
    float* __restrict__ wB,            // f_{n0+K-1}
    float* __restrict__ vel2,          // v2/12 table: written by chunk 0,
                                       // read by chunks 1+
    const int2* __restrict__ thrTab,   // NTILES x NTHR
    const float* __restrict__ srcT,
    int n0)
{
    __shared__ __align__(16) float L0[LROWS * WCOLS];
    __shared__ __align__(16) float L1[LROWS * WCOLS];

    const int tid = threadIdx.x;
    const int blk = blockIdx.x;
    const int b   = blk >> 6;          // batch
    const int tb  = blk & 63;          // tile
    const int gi0 = (tb >> 3) << 6;
    const int gj0 = (tb & 7) << 6;
    const int bi0 = gi0 - 32;
    const int bj0 = gj0 - 32;

    const int grp  = tid >> 6;         // 0..15
    const int lane = tid & 63;
    const int r0   = grp << 3;         // own window rows r0..r0+7
    const int c0   = lane << 1;        // own window cols c0, c0+1
    const int base = (grp + 1) << 2;   // LDS slot base (4 slots/group)

    const bool wbT = (grp >= 4 && grp < 12 && lane >= 16 && lane < 48);

    // ---- prologue ----
    float curR[8][2], prvR[8][2], v2R[8][2];
    if (n0 == 0) {
        // fields start at zero; compute vel2 in registers (once per run) and
        // have interior threads persist the table for chunks 1..15
#pragma unroll
        for (int r = 0; r < 8; ++r) {
            int gi = (bi0 + r0 + r) & 511;
            int gjb = (bj0 + c0) & 511;
#pragma unroll
            for (int c = 0; c < 2; ++c) {
                int gj = gjb + c;
                float v;
                if (gi < 55 || gi >= 457 || gj < 55 || gj >= 457) v = 1e-6f;
                else if (gi >= 128 && gi < 384 && gj >= 128 && gj < 384)
                    v = x[(b << 16) | ((gi - 128) << 8) | (gj - 128)];
                else v = 1.5f;
                float a = (2e-05f * v) / 1e-04f;
                v2R[r][c] = a * a * (1.0f / 12.0f);
                curR[r][c] = 0.0f;
                prvR[r][c] = 0.0f;
            }
        }
        if (wbT) {
            int gj = gj0 + (c0 - 32);
#pragma unroll
            for (int r = 0; r < 8; ++r) {
                int gi = gi0 + (r0 - 32) + r;
                *(float2*)&vel2[(b << 18) | (gi << 9) | gj] =
                    make_float2(v2R[r][0], v2R[r][1]);
            }
        }
    } else {
        const float* gAb = gA + (b << 18);
        const float* gBb = gB + (b << 18);
        const float* gVb = vel2 + (b << 18);
#pragma unroll
        for (int r = 0; r < 8; ++r) {
            int gi = (bi0 + r0 + r) & 511;
            int gj = (bj0 + c0) & 511;
            float2 cv = *(const float2*)&gAb[(gi << 9) | gj];
            float2 pv = *(const float2*)&gBb[(gi << 9) | gj];
            float2 vv = *(const float2*)&gVb[(gi << 9) | gj];
            curR[r][0] = cv.x; curR[r][1] = cv.y;
            prvR[r][0] = pv.x; prvR[r][1] = pv.y;
            v2R[r][0] = vv.x; v2R[r][1] = vv.y;
        }
    }

    // ---- inj/meas descriptor ----
    const int2 tw = thrTab[(tb << 10) | tid];
    int injCell = -1;  float injV = 0.0f;
    if (tw.x >= 0) { injCell = tw.x & 15; injV = 0.09f * se[tw.x >> 8]; }
    int m1Cell = -1, m1Addr = 0, m2Cell = -1, m2Addr = 0;
    {
        int h1 = tw.y & 0xFFFF, h2 = (tw.y >> 16) & 0xFFFF;
        if (h1 & 0x8000) { m1Cell = (h1 >> 8) & 15; m1Addr = (b << 16) | ((h1 & 255) << 8); }
        if (h2 & 0x8000) { m2Cell = (h2 >> 8) & 15; m2Addr = (b << 16) | ((h2 & 255) << 8); }
    }
    const bool rare = (injCell >= 0) || (m1Cell >= 0) || (m2Cell >= 0);

    // ---- publish f_{n0} boundary rows (0,1,6,7) ----
    *(float2*)&L0[(base + 0) * WCOLS + c0] = make_float2(curR[0][0], curR[0][1]);
    *(float2*)&L0[(base + 1) * WCOLS + c0] = make_float2(curR[1][0], curR[1][1]);
    *(float2*)&L0[(base + 2) * WCOLS + c0] = make_float2(curR[6][0], curR[6][1]);
    *(float2*)&L0[(base + 3) * WCOLS + c0] = make_float2(curR[7][0], curR[7][1]);
    __syncthreads();

#pragma unroll 1
    for (int s = 0; s < K; s += 2) {    // 2 steps/iter — body fits I-cache
        float sva = srcT[n0 + s];
        float svb = srcT[n0 + s + 1];

        do_step(L0, L1, v2R, curR, prvR, base, c0);    // prvR <- f_{n+1}
        if (rare) patch_step(prvR, L1, out, base, c0, injCell, injV * sva,
                             m1Cell, m1Addr, m2Cell, m2Addr, n0 + s);
        __syncthreads();

        do_step(L1, L0, v2R, prvR, curR, base, c0);    // curR <- f_{n+2}
        if (rare) patch_step(curR, L0, out, base, c0, injCell, injV * svb,
                             m1Cell, m1Addr, m2Cell, m2Addr, n0 + s + 1);
        if (s + 2 < K) __syncthreads();
    }

    // ---- write back interior: curR = f_{n0+K}, prvR = f_{n0+K-1} ----
    if (wbT) {
        int gj = gj0 + (c0 - 32);
#pragma unroll
        for (int r = 0; r < 8; ++r) {
            int gi = gi0 + (r0 - 32) + r;
            *(float2*)&wA[(b << 18) | (gi << 9) | gj] =
                make_float2(curR[r][0], curR[r][1]);
            *(float2*)&wB[(b << 18) | (gi << 9) | gj] =
                make_float2(prvR[r][0], prvR[r][1]);
        }
    }
}

// ---------------------------------------------------------------------------
extern "C" void kernel_launch(void* const* d_in, const int* in_sizes, int n_in,
                              void* d_out, int out_size, void* d_ws, size_t ws_size,
                              hipStream_t stream) {
    const float* x  = (const float*)d_in[0];
    const float* se = (const float*)d_in[1];
    float* out = (float*)d_out;

    float* ws = (float*)d_ws;
    const int FSZ = NB * NPTS;                 // 4 MB per field (floats)
    float* f[4]  = {ws, ws + FSZ, ws + 2 * FSZ, ws + 3 * FSZ};
    float* dVel  = ws + 4 * FSZ;                        // 4 MB, written chunk 0
    int*   dBlob = (int*)(ws + 5 * FSZ);
    int2*  dTT   = (int2*)dBlob;                        // 64*1024 int2
    float* dSrc  = (float*)(dBlob + NTILES * NTHR * 2);

    // ---- host tables, single blob, single H2D copy ----
    static int h_blob[NTILES * NTHR * 2 + NT];
    int*   h_tt  = h_blob;
    static float h_src[NT];
    static int h_mx[NM], h_my[NM];
    for (int m = 0; m < NM; ++m) {
        double theta = (2.0 * M_PI * (double)m) / 256.0;
        h_mx[m] = (int)(256.0 + 200.0 * cos(theta));
        h_my[m] = (int)(256.0 + 200.0 * sin(theta));
    }
    for (int i = 0; i < NTILES * NTHR; ++i) { h_tt[2*i] = -1; h_tt[2*i+1] = 0; }
    for (int tile = 0; tile < NTILES; ++tile) {
        int bi0 = ((tile >> 3) << 6) - 32;
        int bj0 = ((tile & 7) << 6) - 32;
        for (int m = 0; m < NM; ++m) {
            int d = (h_mx[m] - bi0) & 511;
            int e = (h_my[m] - bj0) & 511;
            if (d >= WROWS || e >= WCOLS) continue;
            int tidx = (d >> 3) * 64 + (e >> 1);         // 16 groups x 64 lanes
            int cell = ((d & 7) << 1) | (e & 1);         // 0..15
            int basei = (tile * NTHR + tidx) * 2;
            if ((m & 3) == 0) h_tt[basei] = ((m >> 2) << 8) | cell;
            if (d >= 32 && d < 96 && e >= 32 && e < 96) {
                int pk = 0x8000 | (cell << 8) | m;
                if (!(h_tt[basei + 1] & 0x8000)) h_tt[basei + 1] |= pk;
                else                             h_tt[basei + 1] |= pk << 16;
            }
        }
    }
    for (int t = 0; t < NT; ++t) {
        float tj  = (float)t * 2e-05f;
        float arg = (float)(2.0 * M_PI * 500.0) * tj;
        float d   = tj - 0.002f;
        float e   = -(d * d) / (float)(2.0 * 0.001 * 0.001);
        h_src[t]  = sinf(arg) * expf(e);
    }
    memcpy(&h_blob[NTILES * NTHR * 2], h_src, sizeof(h_src));
    hipMemcpyAsync(dBlob, h_blob, sizeof(h_blob), hipMemcpyHostToDevice, stream);

    for (int c = 0; c < NCH; ++c) {
        int p = c & 1, q = p ^ 1;
        chunk_kernel<<<NB * NTILES, NTHR, 0, stream>>>(
            x, se, out,
            f[2 * p], f[2 * p + 1],     // unused when c==0 (fields are zero)
            f[2 * q], f[2 * q + 1],
            dVel, dTT, dSrc, c * K);
    }
}